// Round 7
// baseline (357.516 us; speedup 1.0000x reference)
//
#include <hip/hip_runtime.h>
#include <cstdint>

#define IN_F 4096
#define OUT_F 11008
#define NG 32
#define BM 64
#define BN 64
#define BK 64
#define NKT 64
#define NBLK 1376

typedef _Float16 half8 __attribute__((ext_vector_type(8)));
typedef _Float16 h2 __attribute__((ext_vector_type(2)));
typedef float f32x4 __attribute__((ext_vector_type(4)));

__device__ __forceinline__ int dq2(int u0, int u1, h2 sv, h2 bv) {
    // (q | 0x6400) as f16 = 1024+q exactly (q in [0,16)); subtract, then fma
    uint32_t t = ((uint32_t)u0 | ((uint32_t)u1 << 16)) | 0x64006400u;
    h2 v = __builtin_bit_cast(h2, t);
    v = v - (h2){(_Float16)1024.0f, (_Float16)1024.0f};
    v = v * sv + bv;
    return __builtin_bit_cast(int, v);
}

// nibble-packed variant: dword w holds 8 elems, pos i<4 = elem 2i, pos i+4 =
// elem 2i+1, so ((w>>sh)&0x000F000F)|0x6400... yields the k-adjacent f16 pair.
__device__ __forceinline__ int dqn(uint32_t w, int sh, h2 sv, h2 bv) {
    uint32_t t = ((w >> sh) & 0x000F000Fu) | 0x64006400u;
    h2 v = __builtin_bit_cast(h2, t);
    v = v - (h2){(_Float16)1024.0f, (_Float16)1024.0f};
    v = v * sv + bv;
    return __builtin_bit_cast(int, v);
}

// ---------- fused prepass (R6-verified): cvt_x + pack_w in one launch ------
__global__ __launch_bounds__(256) void prep_all(const float* __restrict__ x,
                                                _Float16* __restrict__ xh,
                                                const int* __restrict__ qw,
                                                uint32_t* __restrict__ pwT) {
    const int b = blockIdx.x;
    if (b < 1024) {
        // x fp32 -> f16, 8 elems/thread, fully coalesced
        int i = (b * 256 + threadIdx.x) * 8;
        float4 f0 = *(const float4*)(x + i);
        float4 f1 = *(const float4*)(x + i + 4);
        int4 o;
        o.x = __builtin_bit_cast(int, __builtin_amdgcn_cvt_pkrtz(f0.x, f0.y));
        o.y = __builtin_bit_cast(int, __builtin_amdgcn_cvt_pkrtz(f0.z, f0.w));
        o.z = __builtin_bit_cast(int, __builtin_amdgcn_cvt_pkrtz(f1.x, f1.y));
        o.w = __builtin_bit_cast(int, __builtin_amdgcn_cvt_pkrtz(f1.z, f1.w));
        *(int4*)(xh + i) = o;
    } else {
        // q_weight int32 -> packed nibbles, GEMM-tile order (R1-verified):
        // dword_idx(strip, kt, row, g8) = ((strip*64+kt)*64+row)*8 + g8
        const int bb = b - 1024;               // 172*16 = 2752 blocks
        const int strip = bb >> 4, kc = bb & 15;
        const int tid = threadIdx.x;
        const int i = tid & 31, rhalf = tid >> 5;
        const int kbase = kc * 256 + i * 8;
#pragma unroll
        for (int p = 0; p < 8; ++p) {
            const int row = p * 8 + rhalf;
            const int orow = strip * 64 + row;
            const int4* src = (const int4*)(qw + (size_t)orow * IN_F + kbase);
            int4 q0 = src[0], q1 = src[1];
            // e0..e7 = q0.x q0.y q0.z q0.w q1.x q1.y q1.z q1.w
            uint32_t w = (uint32_t)q0.x | ((uint32_t)q0.z << 4)
                       | ((uint32_t)q1.x << 8) | ((uint32_t)q1.z << 12)
                       | ((uint32_t)q0.y << 16) | ((uint32_t)q0.w << 20)
                       | ((uint32_t)q1.y << 24) | ((uint32_t)q1.w << 28);
            const int kt = kc * 4 + (i >> 3), g8 = i & 7;
            pwT[((size_t)(strip * 64 + kt) * 64 + row) * 8 + g8] = w;
        }
    }
}

// ---------- standalone cvt_x (fallback path) -------------------------------
__global__ __launch_bounds__(256) void cvt_x(const float* __restrict__ x,
                                             _Float16* __restrict__ xh) {
    int i = (blockIdx.x * 256 + threadIdx.x) * 8;
    float4 f0 = *(const float4*)(x + i);
    float4 f1 = *(const float4*)(x + i + 4);
    int4 o;
    o.x = __builtin_bit_cast(int, __builtin_amdgcn_cvt_pkrtz(f0.x, f0.y));
    o.y = __builtin_bit_cast(int, __builtin_amdgcn_cvt_pkrtz(f0.z, f0.w));
    o.z = __builtin_bit_cast(int, __builtin_amdgcn_cvt_pkrtz(f1.x, f1.y));
    o.w = __builtin_bit_cast(int, __builtin_amdgcn_cvt_pkrtz(f1.z, f1.w));
    *(int4*)(xh + i) = o;
}

// ---------- v10 A macros: 64-row tile (2 chunks instead of 4) --------------
#define PF_A10(kt) do {                                                        \
    const _Float16* _p = xh + (size_t)(m0 + rg) * IN_F + (kt) * BK + c8 * 8;   \
    aP0 = *(const int4*)(_p);                                                  \
    aP1 = *(const int4*)(_p + (size_t)32 * IN_F);                              \
} while (0)

#define STAGE_A10(buf) do {                                                    \
    *(int4*)&As[buf][(rg)      * BK + xo] = aP0;                               \
    *(int4*)&As[buf][(rg + 32) * BK + xo] = aP1;                               \
} while (0)

// ---------- B macros (byte-identical to R1/R6 champion) --------------------
#define PF_BP(kt, S) do {                                                      \
    const int _g = (kt) >> 1;                                                  \
    (q##S) = *(const int2*)(pwT + (((size_t)(strip * 64 + (kt))) << 9)         \
                                 + (tid << 1));                                \
    (s##S) = sc [(size_t)(n0 + rn) * NG + _g];                                 \
    (z##S) = zpt[(size_t)(n0 + rn) * NG + _g];                                 \
} while (0)

#define STAGE_BP(buf, S) do {                                                  \
    float _s = (s##S); _Float16 _hs = (_Float16)_s;                            \
    _Float16 _hb = (_Float16)(-(z##S) * _s);                                   \
    h2 _sv = {_hs, _hs}, _bv = {_hb, _hb};                                     \
    uint32_t _w0 = (uint32_t)(q##S).x, _w1 = (uint32_t)(q##S).y;               \
    int4 _o;                                                                   \
    _o.x = dqn(_w0, 0, _sv, _bv); _o.y = dqn(_w0, 4, _sv, _bv);                \
    _o.z = dqn(_w0, 8, _sv, _bv); _o.w = dqn(_w0, 12, _sv, _bv);               \
    *(int4*)&Bs[buf][bo0] = _o;                                                \
    _o.x = dqn(_w1, 0, _sv, _bv); _o.y = dqn(_w1, 4, _sv, _bv);                \
    _o.z = dqn(_w1, 8, _sv, _bv); _o.w = dqn(_w1, 12, _sv, _bv);               \
    *(int4*)&Bs[buf][bo1] = _o;                                                \
} while (0)

// ---------- main GEMM v10: champion dataflow, 64x64 tile for occupancy -----
// R6 post-mortem: latency-bound at 24% occupancy (3 blocks/CU LDS cap, 2.7
// avg grid). BM 128->64: LDS 48->32 KB (5 blocks/CU), grid 688->1376 (5.4
// avg) -> ~20 waves/CU. B path byte-identical; A same macros, fewer chunks.
__global__ __launch_bounds__(256, 5) void qlin_mfma10(
    const _Float16* __restrict__ xh, const uint32_t* __restrict__ pwT,
    const float* __restrict__ sc, const float* __restrict__ zpt,
    const float* __restrict__ bias, float* __restrict__ out)
{
    __shared__ __align__(16) _Float16 As[2][BM * BK]; // 2 x 8 KB
    __shared__ __align__(16) _Float16 Bs[2][BN * BK]; // 2 x 8 KB

    const int tid = threadIdx.x;
    // XCD-colocation swizzle, extended to 1376 = 172 strips x 8 mblk.
    // Groups of 64 blocks = 8 strips x 8 mblk land on one XCD's round.
    int L = blockIdx.x, strip, mblk;
    if (L < 1344) { int p = L >> 6, i = L & 63; strip = p * 8 + (i & 7); mblk = i >> 3; }
    else          { int i = L - 1344;           strip = 168 + (i & 3);   mblk = i >> 2; }
    const int m0 = mblk * BM;
    const int n0 = strip * BN;

    const int lane = tid & 63;
    const int w    = tid >> 6;
    const int wm   = (w & 1) * 32;        // wave quadrant: 32x32 out
    const int wn   = (w >> 1) * 32;
    const int l16  = lane & 15;
    const int quad = lane >> 4;

    const int c8 = tid & 7;               // A: 16B granule within 64-elem row
    const int rg = tid >> 3;              // A: 0..31
    const int xo = (c8 ^ (rg & 7)) << 3;  // A: XOR-swizzled slot

    const int c2 = tid & 3;               // B: 16-elem granule
    const int rn = tid >> 2;              // B: row 0..63
    const int bo0 = rn * BK + ((((c2 << 1)    ) ^ (rn & 7)) << 3);
    const int bo1 = rn * BK + ((((c2 << 1) | 1) ^ (rn & 7)) << 3);

    int4 aP0, aP1;                        // A f16 prefetch (dist-1)
    int2 qA, qB; float sA, zA, sB, zB;    // B packed prefetch (dist-2)

    f32x4 acc[2][2];
#pragma unroll
    for (int mt = 0; mt < 2; ++mt)
#pragma unroll
        for (int nt = 0; nt < 2; ++nt)
            acc[mt][nt] = (f32x4){0.f, 0.f, 0.f, 0.f};

    auto compute = [&](int buf) {
#pragma unroll
        for (int ks = 0; ks < 2; ++ks) {
            half8 a[2], b[2];
            const int ck = ks * 4 + quad;
#pragma unroll
            for (int mt = 0; mt < 2; ++mt) {
                int row = wm + mt * 16 + l16;
                a[mt] = *(const half8*)&As[buf][row * BK + ((ck ^ (row & 7)) << 3)];
            }
#pragma unroll
            for (int nt = 0; nt < 2; ++nt) {
                int row = wn + nt * 16 + l16;
                b[nt] = *(const half8*)&Bs[buf][row * BK + ((ck ^ (row & 7)) << 3)];
            }
#pragma unroll
            for (int mt = 0; mt < 2; ++mt)
#pragma unroll
                for (int nt = 0; nt < 2; ++nt)
                    acc[mt][nt] = __builtin_amdgcn_mfma_f32_16x16x32_f16(
                        a[mt], b[nt], acc[mt][nt], 0, 0, 0);
        }
    };

    // prologue: tile0 staged into buf0; setB holds tile1; setA refilled to tile2
    PF_BP(0, A);
    PF_A10(0);
    PF_BP(1, B);
    STAGE_A10(0);
    STAGE_BP(0, A);
    PF_A10(1);
    PF_BP(2, A);
    __syncthreads();

#pragma unroll 1
    for (int kt = 0; kt < NKT; kt += 2) {
        // even tile: stage kt+1 (aP, setB) into buf1 FIRST, then compute buf0
        {
            STAGE_A10(1);
            STAGE_BP(1, B);
            int ka = kt + 2 < NKT ? kt + 2 : NKT - 1;
            int kb = kt + 3 < NKT ? kt + 3 : NKT - 1;
            PF_A10(ka);
            PF_BP(kb, B);
        }
        compute(0);
        __syncthreads();
        // odd tile: stage kt+2 (aP, setA) into buf0, compute buf1
        if (kt + 2 < NKT) {
            STAGE_A10(0);
            STAGE_BP(0, A);
            int ka = kt + 3 < NKT ? kt + 3 : NKT - 1;
            int kb = kt + 4 < NKT ? kt + 4 : NKT - 1;
            PF_A10(ka);
            PF_BP(kb, A);
        }
        compute(1);
        __syncthreads();
    }

    // epilogue: C/D layout col = lane&15, row = quad*4 + r (verified)
#pragma unroll
    for (int nt = 0; nt < 2; ++nt) {
        int n = n0 + wn + nt * 16 + l16;
        float bv = bias[n];
#pragma unroll
        for (int mt = 0; mt < 2; ++mt) {
            int mb = m0 + wm + mt * 16 + quad * 4;
#pragma unroll
            for (int r = 0; r < 4; ++r)
                out[(size_t)(mb + r) * OUT_F + n] = acc[mt][nt][r] + bv;
        }
    }
}

// ---------- fallback 1 (ws >= 4 MB): f16 A, int32 B via LDS (proven) -------
#define PF_A5(kt) do {                                                         \
    const _Float16* _p = xh + (size_t)(m0 + rg) * IN_F + (kt) * BK + c8 * 8;   \
    aP0 = *(const int4*)(_p);                                                  \
    aP1 = *(const int4*)(_p + (size_t)32 * IN_F);                              \
    aP2 = *(const int4*)(_p + (size_t)64 * IN_F);                              \
    aP3 = *(const int4*)(_p + (size_t)96 * IN_F);                              \
} while (0)

#define STAGE_A5(buf) do {                                                     \
    *(int4*)&As[buf][(rg)      * 64 + xo] = aP0;                               \
    *(int4*)&As[buf][(rg + 32) * 64 + xo] = aP1;                               \
    *(int4*)&As[buf][(rg + 64) * 64 + xo] = aP2;                               \
    *(int4*)&As[buf][(rg + 96) * 64 + xo] = aP3;                               \
} while (0)

#define PF_B(kt, S) do {                                                       \
    const int _k0 = (kt) * 64; const int _g = (kt) >> 1;                       \
    const int* _p0 = qw + (size_t)(n0 + rg) * IN_F + _k0 + c8 * 8;             \
    (q##S##0) = *(const int4*)(_p0);                                           \
    (q##S##1) = *(const int4*)(_p0 + 4);                                       \
    (q##S##2) = *(const int4*)(_p0 + (size_t)32 * IN_F);                       \
    (q##S##3) = *(const int4*)(_p0 + (size_t)32 * IN_F + 4);                   \
    (s##S##0) = sc [(size_t)(n0 + rg) * NG + _g];                              \
    (s##S##1) = sc [(size_t)(n0 + rg + 32) * NG + _g];                         \
    (z##S##0) = zpt[(size_t)(n0 + rg) * NG + _g];                              \
    (z##S##1) = zpt[(size_t)(n0 + rg + 32) * NG + _g];                         \
} while (0)

#define STAGE_B(buf, S) do {                                                   \
    float _s0 = (s##S##0); _Float16 _h0 = (_Float16)_s0;                       \
    _Float16 _b0 = (_Float16)(-(z##S##0) * _s0);                               \
    h2 _sv0 = {_h0, _h0}, _bv0 = {_b0, _b0};                                   \
    int4 _o;                                                                   \
    _o.x = dq2((q##S##0).x, (q##S##0).y, _sv0, _bv0);                          \
    _o.y = dq2((q##S##0).z, (q##S##0).w, _sv0, _bv0);                          \
    _o.z = dq2((q##S##1).x, (q##S##1).y, _sv0, _bv0);                          \
    _o.w = dq2((q##S##1).z, (q##S##1).w, _sv0, _bv0);                          \
    *(int4*)&Bs[buf][(rg) * 64 + xo] = _o;                                     \
    float _s1 = (s##S##1); _Float16 _h1 = (_Float16)_s1;                       \
    _Float16 _b1 = (_Float16)(-(z##S##1) * _s1);                               \
    h2 _sv1 = {_h1, _h1}, _bv1 = {_b1, _b1};                                   \
    _o.x = dq2((q##S##2).x, (q##S##2).y, _sv1, _bv1);                          \
    _o.y = dq2((q##S##2).z, (q##S##2).w, _sv1, _bv1);                          \
    _o.z = dq2((q##S##3).x, (q##S##3).y, _sv1, _bv1);                          \
    _o.w = dq2((q##S##3).z, (q##S##3).w, _sv1, _bv1);                          \
    *(int4*)&Bs[buf][(rg + 32) * 64 + xo] = _o;                                \
} while (0)

__global__ __launch_bounds__(256, 3) void qlin_mfma5(
    const _Float16* __restrict__ xh, const int* __restrict__ qw,
    const float* __restrict__ sc, const float* __restrict__ zpt,
    const float* __restrict__ bias, float* __restrict__ out)
{
    __shared__ __align__(16) _Float16 As[2][128 * 64];
    __shared__ __align__(16) _Float16 Bs[2][64 * 64];

    const int tid = threadIdx.x;
    int L = blockIdx.x, strip, mblk;
    if (L < 672) { int p = L >> 5, i = L & 31; strip = p * 8 + (i & 7); mblk = i >> 3; }
    else         { int i = L - 672;            strip = 168 + (i & 3);   mblk = i >> 2; }
    const int m0 = mblk * 128;
    const int n0 = strip * 64;

    const int lane = tid & 63;
    const int w    = tid >> 6;
    const int wm   = (w & 1) * 64;
    const int wn   = (w >> 1) * 32;
    const int l16  = lane & 15;
    const int quad = lane >> 4;

    const int c8 = tid & 7;
    const int rg = tid >> 3;
    const int xo = (c8 ^ (rg & 7)) << 3;

    int4 aP0, aP1, aP2, aP3;
    int4 qA0, qA1, qA2, qA3; float sA0, sA1, zA0, zA1;
    int4 qB0, qB1, qB2, qB3; float sB0, sB1, zB0, zB1;

    f32x4 acc[4][2];
#pragma unroll
    for (int mt = 0; mt < 4; ++mt)
#pragma unroll
        for (int nt = 0; nt < 2; ++nt)
            acc[mt][nt] = (f32x4){0.f, 0.f, 0.f, 0.f};

    auto compute = [&](int buf) {
#pragma unroll
        for (int ks = 0; ks < 2; ++ks) {
            half8 a[4], b[2];
            const int ck = ks * 4 + quad;
#pragma unroll
            for (int mt = 0; mt < 4; ++mt) {
                int row = wm + mt * 16 + l16;
                a[mt] = *(const half8*)&As[buf][row * 64 + ((ck ^ (row & 7)) << 3)];
            }
#pragma unroll
            for (int nt = 0; nt < 2; ++nt) {
                int row = wn + nt * 16 + l16;
                b[nt] = *(const half8*)&Bs[buf][row * 64 + ((ck ^ (row & 7)) << 3)];
            }
#pragma unroll
            for (int mt = 0; mt < 4; ++mt)
#pragma unroll
                for (int nt = 0; nt < 2; ++nt)
                    acc[mt][nt] = __builtin_amdgcn_mfma_f32_16x16x32_f16(
                        a[mt], b[nt], acc[mt][nt], 0, 0, 0);
        }
    };

    PF_B(0, A);
    PF_A5(0);
    PF_B(1, B);
    STAGE_A5(0);
    STAGE_B(0, A);
    PF_A5(1);
    PF_B(2, A);
    __syncthreads();

#pragma unroll 1
    for (int kt = 0; kt < NKT; kt += 2) {
        {
            STAGE_A5(1);
            STAGE_B(1, B);
            int ka = kt + 2 < NKT ? kt + 2 : NKT - 1;
            int kb = kt + 3 < NKT ? kt + 3 : NKT - 1;
            PF_A5(ka);
            PF_B(kb, B);
        }
        compute(0);
        __syncthreads();
        if (kt + 2 < NKT) {
            STAGE_A5(0);
            STAGE_B(0, A);
            int ka = kt + 3 < NKT ? kt + 3 : NKT - 1;
            int kb = kt + 4 < NKT ? kt + 4 : NKT - 1;
            PF_A5(ka);
            PF_B(kb, A);
        }
        compute(1);
        __syncthreads();
    }

#pragma unroll
    for (int nt = 0; nt < 2; ++nt) {
        int n = n0 + wn + nt * 16 + l16;
        float bv = bias[n];
#pragma unroll
        for (int mt = 0; mt < 4; ++mt) {
            int mb = m0 + wm + mt * 16 + quad * 4;
#pragma unroll
            for (int r = 0; r < 4; ++r)
                out[(size_t)(mb + r) * OUT_F + n] = acc[mt][nt][r] + bv;
        }
    }
}

// ---------- fallback 2 (no workspace): fp32 x, dist-1 ----------------------
__global__ __launch_bounds__(256, 3) void qlin_mfma4(
    const float* __restrict__ x, const int* __restrict__ qw,
    const float* __restrict__ sc, const float* __restrict__ zpt,
    const float* __restrict__ bias, float* __restrict__ out)
{
    __shared__ __align__(16) _Float16 As[2][128 * 64];
    __shared__ __align__(16) _Float16 Bs[2][64 * 64];

    const int tid = threadIdx.x;
    int L = blockIdx.x, strip, mblk;
    if (L < 672) { int p = L >> 5, i = L & 31; strip = p * 8 + (i & 7); mblk = i >> 3; }
    else         { int i = L - 672;            strip = 168 + (i & 3);   mblk = i >> 2; }
    const int m0 = mblk * 128;
    const int n0 = strip * 64;

    const int lane = tid & 63;
    const int w    = tid >> 6;
    const int wm   = (w & 1) * 64;
    const int wn   = (w >> 1) * 32;
    const int l16  = lane & 15;
    const int quad = lane >> 4;

    const int c8 = tid & 7;
    const int rg = tid >> 3;

    float4 aP[8];
    int4   bP[4];
    float  sP[2], zP[2];

    auto pf = [&](int kt) {
        const int k0 = kt * 64;
        const int g  = kt >> 1;
#pragma unroll
        for (int j = 0; j < 4; ++j) {
            int row = rg + 32 * j;
            const float4* p = (const float4*)(x + (size_t)(m0 + row) * IN_F + k0 + c8 * 8);
            aP[2 * j]     = p[0];
            aP[2 * j + 1] = p[1];
        }
#pragma unroll
        for (int j = 0; j < 2; ++j) {
            int row = n0 + rg + 32 * j;
            const int4* p = (const int4*)(qw + (size_t)row * IN_F + k0 + c8 * 8);
            bP[2 * j]     = p[0];
            bP[2 * j + 1] = p[1];
            sP[j] = sc [(size_t)row * NG + g];
            zP[j] = zpt[(size_t)row * NG + g];
        }
    };

    auto stage = [&](int buf) {
#pragma unroll
        for (int j = 0; j < 4; ++j) {
            int row = rg + 32 * j;
            float4 f0 = aP[2 * j], f1 = aP[2 * j + 1];
            int4 o;
            o.x = __builtin_bit_cast(int, __builtin_amdgcn_cvt_pkrtz(f0.x, f0.y));
            o.y = __builtin_bit_cast(int, __builtin_amdgcn_cvt_pkrtz(f0.z, f0.w));
            o.z = __builtin_bit_cast(int, __builtin_amdgcn_cvt_pkrtz(f1.x, f1.y));
            o.w = __builtin_bit_cast(int, __builtin_amdgcn_cvt_pkrtz(f1.z, f1.w));
            *(int4*)&As[buf][row * 64 + ((c8 ^ (row & 7)) << 3)] = o;
        }
#pragma unroll
        for (int j = 0; j < 2; ++j) {
            int row = rg + 32 * j;
            float sf = sP[j];
            _Float16 sh = (_Float16)sf;
            _Float16 bh = (_Float16)(-zP[j] * sf);
            h2 sv = {sh, sh}, bv = {bh, bh};
            int4 q0 = bP[2 * j], q1 = bP[2 * j + 1];
            int4 o;
            o.x = dq2(q0.x, q0.y, sv, bv);
            o.y = dq2(q0.z, q0.w, sv, bv);
            o.z = dq2(q1.x, q1.y, sv, bv);
            o.w = dq2(q1.z, q1.w, sv, bv);
            *(int4*)&Bs[buf][row * 64 + ((c8 ^ (row & 7)) << 3)] = o;
        }
    };

    f32x4 acc[4][2];
#pragma unroll
    for (int mt = 0; mt < 4; ++mt)
#pragma unroll
        for (int nt = 0; nt < 2; ++nt)
            acc[mt][nt] = (f32x4){0.f, 0.f, 0.f, 0.f};

    auto compute = [&](int buf) {
#pragma unroll
        for (int ks = 0; ks < 2; ++ks) {
            half8 a[4], b[2];
            const int ck = ks * 4 + quad;
#pragma unroll
            for (int mt = 0; mt < 4; ++mt) {
                int row = wm + mt * 16 + l16;
                a[mt] = *(const half8*)&As[buf][row * 64 + ((ck ^ (row & 7)) << 3)];
            }
#pragma unroll
            for (int nt = 0; nt < 2; ++nt) {
                int row = wn + nt * 16 + l16;
                b[nt] = *(const half8*)&Bs[buf][row * 64 + ((ck ^ (row & 7)) << 3)];
            }
#pragma unroll
            for (int mt = 0; mt < 4; ++mt)
#pragma unroll
                for (int nt = 0; nt < 2; ++nt)
                    acc[mt][nt] = __builtin_amdgcn_mfma_f32_16x16x32_f16(
                        a[mt], b[nt], acc[mt][nt], 0, 0, 0);
        }
    };

    pf(0);
    stage(0);
    __syncthreads();

#pragma unroll 1
    for (int kt = 0; kt < NKT; ++kt) {
        const int buf = kt & 1;
        if (kt + 1 < NKT) {
            pf(kt + 1);
            compute(buf);
            stage(buf ^ 1);
            __syncthreads();
        } else {
            compute(buf);
        }
    }

#pragma unroll
    for (int nt = 0; nt < 2; ++nt) {
        int n = n0 + wn + nt * 16 + l16;
        float bv = bias[n];
#pragma unroll
        for (int mt = 0; mt < 4; ++mt) {
            int mb = m0 + wm + mt * 16 + quad * 4;
#pragma unroll
            for (int r = 0; r < 4; ++r)
                out[(size_t)(mb + r) * OUT_F + n] = acc[mt][nt][r] + bv;
        }
    }
}

extern "C" void kernel_launch(void* const* d_in, const int* in_sizes, int n_in,
                              void* d_out, int out_size, void* d_ws, size_t ws_size,
                              hipStream_t stream) {
    const float* x    = (const float*)d_in[0];
    const int*   qw   = (const int*)d_in[1];
    const float* scp  = (const float*)d_in[2];
    const float* zpp  = (const float*)d_in[3];
    const float* bias = (const float*)d_in[4];
    float* out = (float*)d_out;
    (void)in_sizes; (void)n_in; (void)out_size;

    const size_t XH_BYTES = (size_t)512 * IN_F * sizeof(_Float16);   // 4 MB
    const size_t PW_BYTES = (size_t)OUT_F * IN_F / 2;                // 22.5 MB

    if (ws_size >= XH_BYTES + PW_BYTES) {
        _Float16* xh  = (_Float16*)d_ws;
        uint32_t* pwT = (uint32_t*)((char*)d_ws + XH_BYTES);
        prep_all<<<dim3(1024 + 2752), dim3(256), 0, stream>>>(x, xh, qw, pwT);
        qlin_mfma10<<<dim3(NBLK), dim3(256), 0, stream>>>(xh, pwT, scp, zpp, bias, out);
    } else if (ws_size >= XH_BYTES) {
        _Float16* xh = (_Float16*)d_ws;
        cvt_x<<<dim3(1024), dim3(256), 0, stream>>>(x, xh);
        qlin_mfma5<<<dim3(672 + 16), dim3(256), 0, stream>>>(xh, qw, scp, zpp, bias, out);
    } else {
        qlin_mfma4<<<dim3(672 + 16), dim3(256), 0, stream>>>(x, qw, scp, zpp, bias, out);
    }
}

// Round 8
// 349.977 us; speedup vs baseline: 1.0215x; 1.0215x over previous
//
#include <hip/hip_runtime.h>
#include <cstdint>

#define IN_F 4096
#define OUT_F 11008
#define NG 32
#define BM 128
#define BN 64
#define BK 64
#define NKT 64

typedef _Float16 half8 __attribute__((ext_vector_type(8)));
typedef _Float16 h2 __attribute__((ext_vector_type(2)));
typedef float f32x4 __attribute__((ext_vector_type(4)));

__device__ __forceinline__ int dq2(int u0, int u1, h2 sv, h2 bv) {
    // (q | 0x6400) as f16 = 1024+q exactly (q in [0,16)); subtract, then fma
    uint32_t t = ((uint32_t)u0 | ((uint32_t)u1 << 16)) | 0x64006400u;
    h2 v = __builtin_bit_cast(h2, t);
    v = v - (h2){(_Float16)1024.0f, (_Float16)1024.0f};
    v = v * sv + bv;
    return __builtin_bit_cast(int, v);
}

// nibble-packed variant: dword w holds 8 elems, pos i<4 = elem 2i, pos i+4 =
// elem 2i+1, so ((w>>sh)&0x000F000F)|0x6400... yields the k-adjacent f16 pair.
__device__ __forceinline__ int dqn(uint32_t w, int sh, h2 sv, h2 bv) {
    uint32_t t = ((w >> sh) & 0x000F000Fu) | 0x64006400u;
    h2 v = __builtin_bit_cast(h2, t);
    v = v - (h2){(_Float16)1024.0f, (_Float16)1024.0f};
    v = v * sv + bv;
    return __builtin_bit_cast(int, v);
}

// ---------- fused prepass: cvt_x + pack_w + ZERO out (for atomic GEMM) -----
// blocks [0,1024): x fp32->f16. [1024,3776): pack_w. [3776,5152): zero out.
__global__ __launch_bounds__(256) void prep_all(const float* __restrict__ x,
                                                _Float16* __restrict__ xh,
                                                const int* __restrict__ qw,
                                                uint32_t* __restrict__ pwT,
                                                float* __restrict__ out) {
    const int b = blockIdx.x;
    if (b < 1024) {
        int i = (b * 256 + threadIdx.x) * 8;
        float4 f0 = *(const float4*)(x + i);
        float4 f1 = *(const float4*)(x + i + 4);
        int4 o;
        o.x = __builtin_bit_cast(int, __builtin_amdgcn_cvt_pkrtz(f0.x, f0.y));
        o.y = __builtin_bit_cast(int, __builtin_amdgcn_cvt_pkrtz(f0.z, f0.w));
        o.z = __builtin_bit_cast(int, __builtin_amdgcn_cvt_pkrtz(f1.x, f1.y));
        o.w = __builtin_bit_cast(int, __builtin_amdgcn_cvt_pkrtz(f1.z, f1.w));
        *(int4*)(xh + i) = o;
    } else if (b < 1024 + 2752) {
        // q_weight int32 -> packed nibbles, GEMM-tile order (R1-verified):
        // dword_idx(strip, kt, row, g8) = ((strip*64+kt)*64+row)*8 + g8
        const int bb = b - 1024;
        const int strip = bb >> 4, kc = bb & 15;
        const int tid = threadIdx.x;
        const int i = tid & 31, rhalf = tid >> 5;
        const int kbase = kc * 256 + i * 8;
#pragma unroll
        for (int p = 0; p < 8; ++p) {
            const int row = p * 8 + rhalf;
            const int orow = strip * 64 + row;
            const int4* src = (const int4*)(qw + (size_t)orow * IN_F + kbase);
            int4 q0 = src[0], q1 = src[1];
            uint32_t w = (uint32_t)q0.x | ((uint32_t)q0.z << 4)
                       | ((uint32_t)q1.x << 8) | ((uint32_t)q1.z << 12)
                       | ((uint32_t)q0.y << 16) | ((uint32_t)q0.w << 20)
                       | ((uint32_t)q1.y << 24) | ((uint32_t)q1.w << 28);
            const int kt = kc * 4 + (i >> 3), g8 = i & 7;
            pwT[((size_t)(strip * 64 + kt) * 64 + row) * 8 + g8] = w;
        }
    } else {
        // zero out: 512*11008 f32 = 5,636,096 dwords = 1376 blocks * 4096
        const size_t base = (size_t)(b - 3776) * 4096 + threadIdx.x * 4;
        const int4 z = {0, 0, 0, 0};
#pragma unroll
        for (int j = 0; j < 4; ++j)
            *(int4*)(out + base + j * 1024) = z;
    }
}

// ---------- standalone cvt_x (fallback path) -------------------------------
__global__ __launch_bounds__(256) void cvt_x(const float* __restrict__ x,
                                             _Float16* __restrict__ xh) {
    int i = (blockIdx.x * 256 + threadIdx.x) * 8;
    float4 f0 = *(const float4*)(x + i);
    float4 f1 = *(const float4*)(x + i + 4);
    int4 o;
    o.x = __builtin_bit_cast(int, __builtin_amdgcn_cvt_pkrtz(f0.x, f0.y));
    o.y = __builtin_bit_cast(int, __builtin_amdgcn_cvt_pkrtz(f0.z, f0.w));
    o.z = __builtin_bit_cast(int, __builtin_amdgcn_cvt_pkrtz(f1.x, f1.y));
    o.w = __builtin_bit_cast(int, __builtin_amdgcn_cvt_pkrtz(f1.z, f1.w));
    *(int4*)(xh + i) = o;
}

// ---------- v11 macros: champion tile, single-buffered LDS -----------------
#define PF_A11(kt) do {                                                        \
    const _Float16* _p = xh + (size_t)(m0 + rg) * IN_F + (kt) * BK + c8 * 8;   \
    aP0 = *(const int4*)(_p);                                                  \
    aP1 = *(const int4*)(_p + (size_t)32 * IN_F);                              \
    aP2 = *(const int4*)(_p + (size_t)64 * IN_F);                              \
    aP3 = *(const int4*)(_p + (size_t)96 * IN_F);                              \
} while (0)

#define STAGE_A11() do {                                                       \
    *(int4*)&As[(rg)      * BK + xo] = aP0;                                    \
    *(int4*)&As[(rg + 32) * BK + xo] = aP1;                                    \
    *(int4*)&As[(rg + 64) * BK + xo] = aP2;                                    \
    *(int4*)&As[(rg + 96) * BK + xo] = aP3;                                    \
} while (0)

#define PF_BP11(kt) do {                                                       \
    const int _g = (kt) >> 1;                                                  \
    qA = *(const int2*)(pwT + (((size_t)(strip * 64 + (kt))) << 9)             \
                             + (tid << 1));                                    \
    sA = sc [(size_t)(n0 + rn) * NG + _g];                                     \
    zA = zpt[(size_t)(n0 + rn) * NG + _g];                                     \
} while (0)

#define STAGE_BP11() do {                                                      \
    float _s = sA; _Float16 _hs = (_Float16)_s;                                \
    _Float16 _hb = (_Float16)(-zA * _s);                                       \
    h2 _sv = {_hs, _hs}, _bv = {_hb, _hb};                                     \
    uint32_t _w0 = (uint32_t)qA.x, _w1 = (uint32_t)qA.y;                       \
    int4 _o;                                                                   \
    _o.x = dqn(_w0, 0, _sv, _bv); _o.y = dqn(_w0, 4, _sv, _bv);                \
    _o.z = dqn(_w0, 8, _sv, _bv); _o.w = dqn(_w0, 12, _sv, _bv);               \
    *(int4*)&Bs[bo0] = _o;                                                     \
    _o.x = dqn(_w1, 0, _sv, _bv); _o.y = dqn(_w1, 4, _sv, _bv);                \
    _o.z = dqn(_w1, 8, _sv, _bv); _o.w = dqn(_w1, 12, _sv, _bv);               \
    *(int4*)&Bs[bo1] = _o;                                                     \
} while (0)

// ---------- main GEMM v11: champion dataflow + split-K=2 for occupancy -----
// R7 post-mortem: must raise waves/CU WITHOUT duplicating B dequant (mfma10's
// mistake). Split-K keeps every (strip,kt) dequanted exactly once; grid
// 688->1376; single-buffered LDS 48->24 KB lets ~6 blocks/CU co-reside.
// Barrier total unchanged (2/kt x 32 kt = champion's 1/kt x 64). Output via
// f32 atomicAdd into zeroed buffer (2 commutative adds -> bit-stable).
__global__ __launch_bounds__(256, 6) void qlin_mfma11(
    const _Float16* __restrict__ xh, const uint32_t* __restrict__ pwT,
    const float* __restrict__ sc, const float* __restrict__ zpt,
    const float* __restrict__ bias, float* __restrict__ out)
{
    __shared__ __align__(16) _Float16 As[BM * BK]; // 16 KB (single)
    __shared__ __align__(16) _Float16 Bs[BN * BK]; //  8 KB (single)

    const int tid = threadIdx.x;
    const int L = blockIdx.x;
    const int sk = (L >= 688) ? 1 : 0;     // K-half
    const int T  = L - sk * 688;
    // XCD-colocation swizzle on tile id (champion-verified)
    int strip, mblk;
    if (T < 672) { int p = T >> 5, i = T & 31; strip = p * 8 + (i & 7); mblk = i >> 3; }
    else         { int i = T - 672;            strip = 168 + (i & 3);   mblk = i >> 2; }
    const int m0 = mblk * BM;
    const int n0 = strip * BN;
    const int kt0 = sk * 32, kt1 = kt0 + 32;

    const int lane = tid & 63;
    const int w    = tid >> 6;
    const int wm   = (w & 1) * 64;
    const int wn   = (w >> 1) * 32;
    const int l16  = lane & 15;
    const int quad = lane >> 4;

    const int c8 = tid & 7;               // A: 16B granule within 64-elem row
    const int rg = tid >> 3;              // A: 0..31
    const int xo = (c8 ^ (rg & 7)) << 3;  // A: XOR-swizzled slot

    const int c2 = tid & 3;               // B: 16-elem granule
    const int rn = tid >> 2;              // B: row 0..63
    const int bo0 = rn * BK + ((((c2 << 1)    ) ^ (rn & 7)) << 3);
    const int bo1 = rn * BK + ((((c2 << 1) | 1) ^ (rn & 7)) << 3);

    int4 aP0, aP1, aP2, aP3;              // A f16 prefetch (dist-1)
    int2 qA; float sA, zA;                // B packed prefetch (dist-1)

    f32x4 acc[4][2];
#pragma unroll
    for (int mt = 0; mt < 4; ++mt)
#pragma unroll
        for (int nt = 0; nt < 2; ++nt)
            acc[mt][nt] = (f32x4){0.f, 0.f, 0.f, 0.f};

    auto compute = [&]() {
#pragma unroll
        for (int ks = 0; ks < 2; ++ks) {
            half8 a[4], b[2];
            const int ck = ks * 4 + quad;
#pragma unroll
            for (int mt = 0; mt < 4; ++mt) {
                int row = wm + mt * 16 + l16;
                a[mt] = *(const half8*)&As[row * BK + ((ck ^ (row & 7)) << 3)];
            }
#pragma unroll
            for (int nt = 0; nt < 2; ++nt) {
                int row = wn + nt * 16 + l16;
                b[nt] = *(const half8*)&Bs[row * BK + ((ck ^ (row & 7)) << 3)];
            }
#pragma unroll
            for (int mt = 0; mt < 4; ++mt)
#pragma unroll
                for (int nt = 0; nt < 2; ++nt)
                    acc[mt][nt] = __builtin_amdgcn_mfma_f32_16x16x32_f16(
                        a[mt], b[nt], acc[mt][nt], 0, 0, 0);
        }
    };

    // prologue: regs hold tile kt0
    PF_A11(kt0);
    PF_BP11(kt0);

#pragma unroll 1
    for (int kt = kt0; kt < kt1; ++kt) {
        STAGE_A11();                      // LDS free: prior compute done
        STAGE_BP11();
        int kn = kt + 1 < kt1 ? kt + 1 : kt;
        PF_A11(kn);                       // issue next loads; latency hides
        PF_BP11(kn);                      // under barrier + compute
        __syncthreads();
        compute();
        __syncthreads();
    }

    // epilogue: atomic accumulate (bias folded into K-half 0)
#pragma unroll
    for (int nt = 0; nt < 2; ++nt) {
        int n = n0 + wn + nt * 16 + l16;
        float bv = sk == 0 ? bias[n] : 0.f;
#pragma unroll
        for (int mt = 0; mt < 4; ++mt) {
            int mb = m0 + wm + mt * 16 + quad * 4;
#pragma unroll
            for (int r = 0; r < 4; ++r)
                atomicAdd(&out[(size_t)(mb + r) * OUT_F + n], acc[mt][nt][r] + bv);
        }
    }
}

// ---------- fallback 1 (ws >= 4 MB): f16 A, int32 B via LDS (proven) -------
#define PF_A5(kt) do {                                                         \
    const _Float16* _p = xh + (size_t)(m0 + rg) * IN_F + (kt) * 64 + c8 * 8;   \
    aP0 = *(const int4*)(_p);                                                  \
    aP1 = *(const int4*)(_p + (size_t)32 * IN_F);                              \
    aP2 = *(const int4*)(_p + (size_t)64 * IN_F);                              \
    aP3 = *(const int4*)(_p + (size_t)96 * IN_F);                              \
} while (0)

#define STAGE_A5(buf) do {                                                     \
    *(int4*)&As[buf][(rg)      * 64 + xo] = aP0;                               \
    *(int4*)&As[buf][(rg + 32) * 64 + xo] = aP1;                               \
    *(int4*)&As[buf][(rg + 64) * 64 + xo] = aP2;                               \
    *(int4*)&As[buf][(rg + 96) * 64 + xo] = aP3;                               \
} while (0)

#define PF_B(kt, S) do {                                                       \
    const int _k0 = (kt) * 64; const int _g = (kt) >> 1;                       \
    const int* _p0 = qw + (size_t)(n0 + rg) * IN_F + _k0 + c8 * 8;             \
    (q##S##0) = *(const int4*)(_p0);                                           \
    (q##S##1) = *(const int4*)(_p0 + 4);                                       \
    (q##S##2) = *(const int4*)(_p0 + (size_t)32 * IN_F);                       \
    (q##S##3) = *(const int4*)(_p0 + (size_t)32 * IN_F + 4);                   \
    (s##S##0) = sc [(size_t)(n0 + rg) * NG + _g];                              \
    (s##S##1) = sc [(size_t)(n0 + rg + 32) * NG + _g];                         \
    (z##S##0) = zpt[(size_t)(n0 + rg) * NG + _g];                              \
    (z##S##1) = zpt[(size_t)(n0 + rg + 32) * NG + _g];                         \
} while (0)

#define STAGE_B(buf, S) do {                                                   \
    float _s0 = (s##S##0); _Float16 _h0 = (_Float16)_s0;                       \
    _Float16 _b0 = (_Float16)(-(z##S##0) * _s0);                               \
    h2 _sv0 = {_h0, _h0}, _bv0 = {_b0, _b0};                                   \
    int4 _o;                                                                   \
    _o.x = dq2((q##S##0).x, (q##S##0).y, _sv0, _bv0);                          \
    _o.y = dq2((q##S##0).z, (q##S##0).w, _sv0, _bv0);                          \
    _o.z = dq2((q##S##1).x, (q##S##1).y, _sv0, _bv0);                          \
    _o.w = dq2((q##S##1).z, (q##S##1).w, _sv0, _bv0);                          \
    *(int4*)&Bs[buf][(rg) * 64 + xo] = _o;                                     \
    float _s1 = (s##S##1); _Float16 _h1 = (_Float16)_s1;                       \
    _Float16 _b1 = (_Float16)(-(z##S##1) * _s1);                               \
    h2 _sv1 = {_h1, _h1}, _bv1 = {_b1, _b1};                                   \
    _o.x = dq2((q##S##2).x, (q##S##2).y, _sv1, _bv1);                          \
    _o.y = dq2((q##S##2).z, (q##S##2).w, _sv1, _bv1);                          \
    _o.z = dq2((q##S##3).x, (q##S##3).y, _sv1, _bv1);                          \
    _o.w = dq2((q##S##3).z, (q##S##3).w, _sv1, _bv1);                          \
    *(int4*)&Bs[buf][(rg + 32) * 64 + xo] = _o;                                \
} while (0)

__global__ __launch_bounds__(256, 3) void qlin_mfma5(
    const _Float16* __restrict__ xh, const int* __restrict__ qw,
    const float* __restrict__ sc, const float* __restrict__ zpt,
    const float* __restrict__ bias, float* __restrict__ out)
{
    __shared__ __align__(16) _Float16 As[2][128 * 64];
    __shared__ __align__(16) _Float16 Bs[2][64 * 64];

    const int tid = threadIdx.x;
    int L = blockIdx.x, strip, mblk;
    if (L < 672) { int p = L >> 5, i = L & 31; strip = p * 8 + (i & 7); mblk = i >> 3; }
    else         { int i = L - 672;            strip = 168 + (i & 3);   mblk = i >> 2; }
    const int m0 = mblk * 128;
    const int n0 = strip * 64;

    const int lane = tid & 63;
    const int w    = tid >> 6;
    const int wm   = (w & 1) * 64;
    const int wn   = (w >> 1) * 32;
    const int l16  = lane & 15;
    const int quad = lane >> 4;

    const int c8 = tid & 7;
    const int rg = tid >> 3;
    const int xo = (c8 ^ (rg & 7)) << 3;

    int4 aP0, aP1, aP2, aP3;
    int4 qA0, qA1, qA2, qA3; float sA0, sA1, zA0, zA1;
    int4 qB0, qB1, qB2, qB3; float sB0, sB1, zB0, zB1;

    f32x4 acc[4][2];
#pragma unroll
    for (int mt = 0; mt < 4; ++mt)
#pragma unroll
        for (int nt = 0; nt < 2; ++nt)
            acc[mt][nt] = (f32x4){0.f, 0.f, 0.f, 0.f};

    auto compute = [&](int buf) {
#pragma unroll
        for (int ks = 0; ks < 2; ++ks) {
            half8 a[4], b[2];
            const int ck = ks * 4 + quad;
#pragma unroll
            for (int mt = 0; mt < 4; ++mt) {
                int row = wm + mt * 16 + l16;
                a[mt] = *(const half8*)&As[buf][row * 64 + ((ck ^ (row & 7)) << 3)];
            }
#pragma unroll
            for (int nt = 0; nt < 2; ++nt) {
                int row = wn + nt * 16 + l16;
                b[nt] = *(const half8*)&Bs[buf][row * 64 + ((ck ^ (row & 7)) << 3)];
            }
#pragma unroll
            for (int mt = 0; mt < 4; ++mt)
#pragma unroll
                for (int nt = 0; nt < 2; ++nt)
                    acc[mt][nt] = __builtin_amdgcn_mfma_f32_16x16x32_f16(
                        a[mt], b[nt], acc[mt][nt], 0, 0, 0);
        }
    };

    PF_B(0, A);
    PF_A5(0);
    PF_B(1, B);
    STAGE_A5(0);
    STAGE_B(0, A);
    PF_A5(1);
    PF_B(2, A);
    __syncthreads();

#pragma unroll 1
    for (int kt = 0; kt < NKT; kt += 2) {
        {
            STAGE_A5(1);
            STAGE_B(1, B);
            int ka = kt + 2 < NKT ? kt + 2 : NKT - 1;
            int kb = kt + 3 < NKT ? kt + 3 : NKT - 1;
            PF_A5(ka);
            PF_B(kb, B);
        }
        compute(0);
        __syncthreads();
        if (kt + 2 < NKT) {
            STAGE_A5(0);
            STAGE_B(0, A);
            int ka = kt + 3 < NKT ? kt + 3 : NKT - 1;
            int kb = kt + 4 < NKT ? kt + 4 : NKT - 1;
            PF_A5(ka);
            PF_B(kb, A);
        }
        compute(1);
        __syncthreads();
    }

#pragma unroll
    for (int nt = 0; nt < 2; ++nt) {
        int n = n0 + wn + nt * 16 + l16;
        float bv = bias[n];
#pragma unroll
        for (int mt = 0; mt < 4; ++mt) {
            int mb = m0 + wm + mt * 16 + quad * 4;
#pragma unroll
            for (int r = 0; r < 4; ++r)
                out[(size_t)(mb + r) * OUT_F + n] = acc[mt][nt][r] + bv;
        }
    }
}

// ---------- fallback 2 (no workspace): fp32 x, dist-1 ----------------------
__global__ __launch_bounds__(256, 3) void qlin_mfma4(
    const float* __restrict__ x, const int* __restrict__ qw,
    const float* __restrict__ sc, const float* __restrict__ zpt,
    const float* __restrict__ bias, float* __restrict__ out)
{
    __shared__ __align__(16) _Float16 As[2][128 * 64];
    __shared__ __align__(16) _Float16 Bs[2][64 * 64];

    const int tid = threadIdx.x;
    int L = blockIdx.x, strip, mblk;
    if (L < 672) { int p = L >> 5, i = L & 31; strip = p * 8 + (i & 7); mblk = i >> 3; }
    else         { int i = L - 672;            strip = 168 + (i & 3);   mblk = i >> 2; }
    const int m0 = mblk * 128;
    const int n0 = strip * 64;

    const int lane = tid & 63;
    const int w    = tid >> 6;
    const int wm   = (w & 1) * 64;
    const int wn   = (w >> 1) * 32;
    const int l16  = lane & 15;
    const int quad = lane >> 4;

    const int c8 = tid & 7;
    const int rg = tid >> 3;

    float4 aP[8];
    int4   bP[4];
    float  sP[2], zP[2];

    auto pf = [&](int kt) {
        const int k0 = kt * 64;
        const int g  = kt >> 1;
#pragma unroll
        for (int j = 0; j < 4; ++j) {
            int row = rg + 32 * j;
            const float4* p = (const float4*)(x + (size_t)(m0 + row) * IN_F + k0 + c8 * 8);
            aP[2 * j]     = p[0];
            aP[2 * j + 1] = p[1];
        }
#pragma unroll
        for (int j = 0; j < 2; ++j) {
            int row = n0 + rg + 32 * j;
            const int4* p = (const int4*)(qw + (size_t)row * IN_F + k0 + c8 * 8);
            bP[2 * j]     = p[0];
            bP[2 * j + 1] = p[1];
            sP[j] = sc [(size_t)row * NG + g];
            zP[j] = zpt[(size_t)row * NG + g];
        }
    };

    auto stage = [&](int buf) {
#pragma unroll
        for (int j = 0; j < 4; ++j) {
            int row = rg + 32 * j;
            float4 f0 = aP[2 * j], f1 = aP[2 * j + 1];
            int4 o;
            o.x = __builtin_bit_cast(int, __builtin_amdgcn_cvt_pkrtz(f0.x, f0.y));
            o.y = __builtin_bit_cast(int, __builtin_amdgcn_cvt_pkrtz(f0.z, f0.w));
            o.z = __builtin_bit_cast(int, __builtin_amdgcn_cvt_pkrtz(f1.x, f1.y));
            o.w = __builtin_bit_cast(int, __builtin_amdgcn_cvt_pkrtz(f1.z, f1.w));
            *(int4*)&As[buf][row * 64 + ((c8 ^ (row & 7)) << 3)] = o;
        }
#pragma unroll
        for (int j = 0; j < 2; ++j) {
            int row = rg + 32 * j;
            float sf = sP[j];
            _Float16 sh = (_Float16)sf;
            _Float16 bh = (_Float16)(-zP[j] * sf);
            h2 sv = {sh, sh}, bv = {bh, bh};
            int4 q0 = bP[2 * j], q1 = bP[2 * j + 1];
            int4 o;
            o.x = dq2(q0.x, q0.y, sv, bv);
            o.y = dq2(q0.z, q0.w, sv, bv);
            o.z = dq2(q1.x, q1.y, sv, bv);
            o.w = dq2(q1.z, q1.w, sv, bv);
            *(int4*)&Bs[buf][row * 64 + ((c8 ^ (row & 7)) << 3)] = o;
        }
    };

    f32x4 acc[4][2];
#pragma unroll
    for (int mt = 0; mt < 4; ++mt)
#pragma unroll
        for (int nt = 0; nt < 2; ++nt)
            acc[mt][nt] = (f32x4){0.f, 0.f, 0.f, 0.f};

    auto compute = [&](int buf) {
#pragma unroll
        for (int ks = 0; ks < 2; ++ks) {
            half8 a[4], b[2];
            const int ck = ks * 4 + quad;
#pragma unroll
            for (int mt = 0; mt < 4; ++mt) {
                int row = wm + mt * 16 + l16;
                a[mt] = *(const half8*)&As[buf][row * 64 + ((ck ^ (row & 7)) << 3)];
            }
#pragma unroll
            for (int nt = 0; nt < 2; ++nt) {
                int row = wn + nt * 16 + l16;
                b[nt] = *(const half8*)&Bs[buf][row * 64 + ((ck ^ (row & 7)) << 3)];
            }
#pragma unroll
            for (int mt = 0; mt < 4; ++mt)
#pragma unroll
                for (int nt = 0; nt < 2; ++nt)
                    acc[mt][nt] = __builtin_amdgcn_mfma_f32_16x16x32_f16(
                        a[mt], b[nt], acc[mt][nt], 0, 0, 0);
        }
    };

    pf(0);
    stage(0);
    __syncthreads();

#pragma unroll 1
    for (int kt = 0; kt < NKT; ++kt) {
        const int buf = kt & 1;
        if (kt + 1 < NKT) {
            pf(kt + 1);
            compute(buf);
            stage(buf ^ 1);
            __syncthreads();
        } else {
            compute(buf);
        }
    }

#pragma unroll
    for (int nt = 0; nt < 2; ++nt) {
        int n = n0 + wn + nt * 16 + l16;
        float bv = bias[n];
#pragma unroll
        for (int mt = 0; mt < 4; ++mt) {
            int mb = m0 + wm + mt * 16 + quad * 4;
#pragma unroll
            for (int r = 0; r < 4; ++r)
                out[(size_t)(mb + r) * OUT_F + n] = acc[mt][nt][r] + bv;
        }
    }
}

extern "C" void kernel_launch(void* const* d_in, const int* in_sizes, int n_in,
                              void* d_out, int out_size, void* d_ws, size_t ws_size,
                              hipStream_t stream) {
    const float* x    = (const float*)d_in[0];
    const int*   qw   = (const int*)d_in[1];
    const float* scp  = (const float*)d_in[2];
    const float* zpp  = (const float*)d_in[3];
    const float* bias = (const float*)d_in[4];
    float* out = (float*)d_out;
    (void)in_sizes; (void)n_in; (void)out_size;

    const size_t XH_BYTES = (size_t)512 * IN_F * sizeof(_Float16);   // 4 MB
    const size_t PW_BYTES = (size_t)OUT_F * IN_F / 2;                // 22.5 MB

    if (ws_size >= XH_BYTES + PW_BYTES) {
        _Float16* xh  = (_Float16*)d_ws;
        uint32_t* pwT = (uint32_t*)((char*)d_ws + XH_BYTES);
        prep_all<<<dim3(1024 + 2752 + 1376), dim3(256), 0, stream>>>(x, xh, qw, pwT, out);
        qlin_mfma11<<<dim3(1376), dim3(256), 0, stream>>>(xh, pwT, scp, zpp, bias, out);
    } else if (ws_size >= XH_BYTES) {
        _Float16* xh = (_Float16*)d_ws;
        cvt_x<<<dim3(1024), dim3(256), 0, stream>>>(x, xh);
        qlin_mfma5<<<dim3(688), dim3(256), 0, stream>>>(xh, qw, scp, zpp, bias, out);
    } else {
        qlin_mfma4<<<dim3(688), dim3(256), 0, stream>>>(x, qw, scp, zpp, bias, out);
    }
}

// Round 10
// 331.864 us; speedup vs baseline: 1.0773x; 1.0546x over previous
//
#include <hip/hip_runtime.h>
#include <cstdint>

#define IN_F 4096
#define OUT_F 11008
#define NG 32
#define BM 128
#define BN 64
#define BK 64
#define NKT 64
#define NBLK 688

typedef _Float16 half8 __attribute__((ext_vector_type(8)));
typedef _Float16 h2 __attribute__((ext_vector_type(2)));
typedef float f32x4 __attribute__((ext_vector_type(4)));

__device__ __forceinline__ int dq2(int u0, int u1, h2 sv, h2 bv) {
    // (q | 0x6400) as f16 = 1024+q exactly (q in [0,16)); subtract, then fma
    uint32_t t = ((uint32_t)u0 | ((uint32_t)u1 << 16)) | 0x64006400u;
    h2 v = __builtin_bit_cast(h2, t);
    v = v - (h2){(_Float16)1024.0f, (_Float16)1024.0f};
    v = v * sv + bv;
    return __builtin_bit_cast(int, v);
}

// nibble-packed variant: dword w holds 8 elems, pos i<4 = elem 2i, pos i+4 =
// elem 2i+1, so ((w>>sh)&0x000F000F)|0x6400... yields the k-adjacent f16 pair.
__device__ __forceinline__ int dqn(uint32_t w, int sh, h2 sv, h2 bv) {
    uint32_t t = ((w >> sh) & 0x000F000Fu) | 0x64006400u;
    h2 v = __builtin_bit_cast(h2, t);
    v = v - (h2){(_Float16)1024.0f, (_Float16)1024.0f};
    v = v * sv + bv;
    return __builtin_bit_cast(int, v);
}

// ---------- async global->LDS (16B per lane; dest = wave base + lane*16) ---
__device__ __forceinline__ void gll16(const _Float16* g, _Float16* l) {
    __builtin_amdgcn_global_load_lds(
        (const __attribute__((address_space(1))) uint32_t*)(const void*)g,
        (__attribute__((address_space(3))) uint32_t*)(void*)l, 16, 0, 0);
}

// ---------- fused prepass (R6-verified): cvt_x + pack_w in one launch ------
__global__ __launch_bounds__(256) void prep_all(const float* __restrict__ x,
                                                _Float16* __restrict__ xh,
                                                const int* __restrict__ qw,
                                                uint32_t* __restrict__ pwT) {
    const int b = blockIdx.x;
    if (b < 1024) {
        // x fp32 -> f16, 8 elems/thread, fully coalesced
        int i = (b * 256 + threadIdx.x) * 8;
        float4 f0 = *(const float4*)(x + i);
        float4 f1 = *(const float4*)(x + i + 4);
        int4 o;
        o.x = __builtin_bit_cast(int, __builtin_amdgcn_cvt_pkrtz(f0.x, f0.y));
        o.y = __builtin_bit_cast(int, __builtin_amdgcn_cvt_pkrtz(f0.z, f0.w));
        o.z = __builtin_bit_cast(int, __builtin_amdgcn_cvt_pkrtz(f1.x, f1.y));
        o.w = __builtin_bit_cast(int, __builtin_amdgcn_cvt_pkrtz(f1.z, f1.w));
        *(int4*)(xh + i) = o;
    } else {
        // q_weight int32 -> packed nibbles, GEMM-tile order (R1-verified):
        // dword_idx(strip, kt, row, g8) = ((strip*64+kt)*64+row)*8 + g8
        const int bb = b - 1024;               // 172*16 = 2752 blocks
        const int strip = bb >> 4, kc = bb & 15;
        const int tid = threadIdx.x;
        const int i = tid & 31, rhalf = tid >> 5;
        const int kbase = kc * 256 + i * 8;
#pragma unroll
        for (int p = 0; p < 8; ++p) {
            const int row = p * 8 + rhalf;
            const int orow = strip * 64 + row;
            const int4* src = (const int4*)(qw + (size_t)orow * IN_F + kbase);
            int4 q0 = src[0], q1 = src[1];
            // e0..e7 = q0.x q0.y q0.z q0.w q1.x q1.y q1.z q1.w
            uint32_t w = (uint32_t)q0.x | ((uint32_t)q0.z << 4)
                       | ((uint32_t)q1.x << 8) | ((uint32_t)q1.z << 12)
                       | ((uint32_t)q0.y << 16) | ((uint32_t)q0.w << 20)
                       | ((uint32_t)q1.y << 24) | ((uint32_t)q1.w << 28);
            const int kt = kc * 4 + (i >> 3), g8 = i & 7;
            pwT[((size_t)(strip * 64 + kt) * 64 + row) * 8 + g8] = w;
        }
    }
}

// ---------- standalone cvt_x (fallback path) -------------------------------
__global__ __launch_bounds__(256) void cvt_x(const float* __restrict__ x,
                                             _Float16* __restrict__ xh) {
    int i = (blockIdx.x * 256 + threadIdx.x) * 8;
    float4 f0 = *(const float4*)(x + i);
    float4 f1 = *(const float4*)(x + i + 4);
    int4 o;
    o.x = __builtin_bit_cast(int, __builtin_amdgcn_cvt_pkrtz(f0.x, f0.y));
    o.y = __builtin_bit_cast(int, __builtin_amdgcn_cvt_pkrtz(f0.z, f0.w));
    o.z = __builtin_bit_cast(int, __builtin_amdgcn_cvt_pkrtz(f1.x, f1.y));
    o.w = __builtin_bit_cast(int, __builtin_amdgcn_cvt_pkrtz(f1.z, f1.w));
    *(int4*)(xh + i) = o;
}

// ---------- shared A-path macros (reg round-trip; used by mfma5) -----------
#define PF_A(kt) do {                                                          \
    const _Float16* _p = xh + (size_t)(m0 + rg) * IN_F + (kt) * BK + c8 * 8;   \
    aP0 = *(const int4*)(_p);                                                  \
    aP1 = *(const int4*)(_p + (size_t)32 * IN_F);                              \
    aP2 = *(const int4*)(_p + (size_t)64 * IN_F);                              \
    aP3 = *(const int4*)(_p + (size_t)96 * IN_F);                              \
} while (0)

#define STAGE_A(buf) do {                                                      \
    *(int4*)&As[buf][(rg)      * BK + xo] = aP0;                               \
    *(int4*)&As[buf][(rg + 32) * BK + xo] = aP1;                               \
    *(int4*)&As[buf][(rg + 64) * BK + xo] = aP2;                               \
    *(int4*)&As[buf][(rg + 96) * BK + xo] = aP3;                               \
} while (0)

// ---------- v12 A macro: direct global->LDS DMA, pre-swizzled source -------
// Wave w stages rows {j*32 + w*8 .. +8} per issue j; lane l lands at LDS
// slot l&7 of row j*32+w*8+(l>>3). Reader expects slot s of row r to hold
// granule s^(r&7); here r&7 = l>>3, so lane l loads granule (l&7)^(l>>3).
// Bytes land exactly where STAGE_A put them -> reader unchanged, bit-exact.
#define GLL_A(buf, kt) do {                                                    \
    const _Float16* _s = xh + (size_t)(m0 + ar) * IN_F + (kt) * BK + (gs << 3);\
    _Float16* _d = &As[buf][(w * 8) * BK];   /* wave-uniform base */           \
    gll16(_s,                     _d);                                         \
    gll16(_s + (size_t)32 * IN_F, _d + 32 * BK);                               \
    gll16(_s + (size_t)64 * IN_F, _d + 64 * BK);                               \
    gll16(_s + (size_t)96 * IN_F, _d + 96 * BK);                               \
} while (0)

// ---------- B macros (byte-identical to R1/R6 champion) --------------------
#define PF_BP(kt, S) do {                                                      \
    const int _g = (kt) >> 1;                                                  \
    (q##S) = *(const int2*)(pwT + (((size_t)(strip * 64 + (kt))) << 9)         \
                                 + (tid << 1));                                \
    (s##S) = sc [(size_t)(n0 + rn) * NG + _g];                                 \
    (z##S) = zpt[(size_t)(n0 + rn) * NG + _g];                                 \
} while (0)

#define STAGE_BP(buf, S) do {                                                  \
    float _s = (s##S); _Float16 _hs = (_Float16)_s;                            \
    _Float16 _hb = (_Float16)(-(z##S) * _s);                                   \
    h2 _sv = {_hs, _hs}, _bv = {_hb, _hb};                                     \
    uint32_t _w0 = (uint32_t)(q##S).x, _w1 = (uint32_t)(q##S).y;               \
    int4 _o;                                                                   \
    _o.x = dqn(_w0, 0, _sv, _bv); _o.y = dqn(_w0, 4, _sv, _bv);                \
    _o.z = dqn(_w0, 8, _sv, _bv); _o.w = dqn(_w0, 12, _sv, _bv);               \
    *(int4*)&Bs[buf][bo0] = _o;                                                \
    _o.x = dqn(_w1, 0, _sv, _bv); _o.y = dqn(_w1, 4, _sv, _bv);                \
    _o.z = dqn(_w1, 8, _sv, _bv); _o.w = dqn(_w1, 12, _sv, _bv);               \
    *(int4*)&Bs[buf][bo1] = _o;                                                \
} while (0)

// ---------- main GEMM v12: champion + global_load_lds A-stage --------------
// R8 post-mortem: occupancy is NOT the binding constraint (R7: 32% occ, same
// dur; R8: split-K, regressed). The lever is the stage chain itself: replace
// A's global->reg->LDS round-trip with direct DMA (guide Common-mistake #1:
// width=16 global_load_lds, compiler never auto-emits). B path, tile,
// swizzle, barriers: byte-identical to the R6 champion.
__global__ __launch_bounds__(256, 3) void qlin_mfma12(
    const _Float16* __restrict__ xh, const uint32_t* __restrict__ pwT,
    const float* __restrict__ sc, const float* __restrict__ zpt,
    const float* __restrict__ bias, float* __restrict__ out)
{
    __shared__ __align__(16) _Float16 As[2][BM * BK]; // 16 KB each
    __shared__ __align__(16) _Float16 Bs[2][BN * BK]; //  8 KB each

    const int tid = threadIdx.x;
    // XCD-colocation swizzle (proven: FETCH 936->219->175 MB)
    int L = blockIdx.x, strip, mblk;
    if (L < 672) { int p = L >> 5, i = L & 31; strip = p * 8 + (i & 7); mblk = i >> 3; }
    else         { int i = L - 672;            strip = 168 + (i & 3);   mblk = i >> 2; }
    const int m0 = mblk * BM;
    const int n0 = strip * BN;

    const int lane = tid & 63;
    const int w    = tid >> 6;
    const int wm   = (w & 1) * 64;
    const int wn   = (w >> 1) * 32;
    const int l16  = lane & 15;
    const int quad = lane >> 4;

    const int ar = w * 8 + (lane >> 3);         // A DMA: row within 32-chunk
    const int gs = (lane & 7) ^ (lane >> 3);    // A DMA: pre-swizzled granule

    const int c2 = tid & 3;               // B: 16-elem granule
    const int rn = tid >> 2;              // B: row 0..63
    const int bo0 = rn * BK + ((((c2 << 1)    ) ^ (rn & 7)) << 3);
    const int bo1 = rn * BK + ((((c2 << 1) | 1) ^ (rn & 7)) << 3);

    int2 qA, qB; float sA, zA, sB, zB;    // B packed prefetch (dist-2)

    f32x4 acc[4][2];
#pragma unroll
    for (int mt = 0; mt < 4; ++mt)
#pragma unroll
        for (int nt = 0; nt < 2; ++nt)
            acc[mt][nt] = (f32x4){0.f, 0.f, 0.f, 0.f};

    auto compute = [&](int buf) {
#pragma unroll
        for (int ks = 0; ks < 2; ++ks) {
            half8 a[4], b[2];
            const int ck = ks * 4 + quad;
#pragma unroll
            for (int mt = 0; mt < 4; ++mt) {
                int row = wm + mt * 16 + l16;
                a[mt] = *(const half8*)&As[buf][row * BK + ((ck ^ (row & 7)) << 3)];
            }
#pragma unroll
            for (int nt = 0; nt < 2; ++nt) {
                int row = wn + nt * 16 + l16;
                b[nt] = *(const half8*)&Bs[buf][row * BK + ((ck ^ (row & 7)) << 3)];
            }
#pragma unroll
            for (int mt = 0; mt < 4; ++mt)
#pragma unroll
                for (int nt = 0; nt < 2; ++nt)
                    acc[mt][nt] = __builtin_amdgcn_mfma_f32_16x16x32_f16(
                        a[mt], b[nt], acc[mt][nt], 0, 0, 0);
        }
    };

    // prologue: B regs first (so their waitcnt retires before gll drains),
    // then A tile0 DMA; Bs tile0 staged; B set A refilled to tile2.
    PF_BP(0, A);
    GLL_A(0, 0);
    PF_BP(1, B);
    STAGE_BP(0, A);
    PF_BP(2, A);
    __syncthreads();                      // drains gll -> As[0] ready

#pragma unroll 1
    for (int kt = 0; kt < NKT; kt += 2) {
        // even tile: DMA A(kt+1)->As[1]; stage B(kt+1) from setB; refill setB
        GLL_A(1, kt + 1);
        STAGE_BP(1, B);
        { int kb = kt + 3 < NKT ? kt + 3 : NKT - 1; PF_BP(kb, B); }
        compute(0);
        __syncthreads();                  // drains gll -> As[1] ready
        // odd tile: DMA A(kt+2)->As[0]; stage B(kt+2) from setA; refill setA
        if (kt + 2 < NKT) {
            GLL_A(0, kt + 2);
            STAGE_BP(0, A);
            int kb = kt + 4 < NKT ? kt + 4 : NKT - 1;
            PF_BP(kb, A);
        }
        compute(1);
        __syncthreads();
    }

    // epilogue: C/D layout col = lane&15, row = quad*4 + r
#pragma unroll
    for (int nt = 0; nt < 2; ++nt) {
        int n = n0 + wn + nt * 16 + l16;
        float bv = bias[n];
#pragma unroll
        for (int mt = 0; mt < 4; ++mt) {
            int mb = m0 + wm + mt * 16 + quad * 4;
#pragma unroll
            for (int r = 0; r < 4; ++r)
                out[(size_t)(mb + r) * OUT_F + n] = acc[mt][nt][r] + bv;
        }
    }
}

// ---------- fallback 1 (ws >= 4 MB): f16 A, int32 B via LDS (proven) -------
#define PF_B(kt, S) do {                                                       \
    const int _k0 = (kt) * BK; const int _g = (kt) >> 1;                       \
    const int* _p0 = qw + (size_t)(n0 + rg) * IN_F + _k0 + c8 * 8;             \
    (q##S##0) = *(const int4*)(_p0);                                           \
    (q##S##1) = *(const int4*)(_p0 + 4);                                       \
    (q##S##2) = *(const int4*)(_p0 + (size_t)32 * IN_F);                       \
    (q##S##3) = *(const int4*)(_p0 + (size_t)32 * IN_F + 4);                   \
    (s##S##0) = sc [(size_t)(n0 + rg) * NG + _g];                              \
    (s##S##1) = sc [(size_t)(n0 + rg + 32) * NG + _g];                         \
    (z##S##0) = zpt[(size_t)(n0 + rg) * NG + _g];                              \
    (z##S##1) = zpt[(size_t)(n0 + rg + 32) * NG + _g];                         \
} while (0)

#define STAGE_B(buf, S) do {                                                   \
    float _s0 = (s##S##0); _Float16 _h0 = (_Float16)_s0;                       \
    _Float16 _b0 = (_Float16)(-(z##S##0) * _s0);                               \
    h2 _sv0 = {_h0, _h0}, _bv0 = {_b0, _b0};                                   \
    int4 _o;                                                                   \
    _o.x = dq2((q##S##0).x, (q##S##0).y, _sv0, _bv0);                          \
    _o.y = dq2((q##S##0).z, (q##S##0).w, _sv0, _bv0);                          \
    _o.z = dq2((q##S##1).x, (q##S##1).y, _sv0, _bv0);                          \
    _o.w = dq2((q##S##1).z, (q##S##1).w, _sv0, _bv0);                          \
    *(int4*)&Bs[buf][(rg) * BK + xo] = _o;                                     \
    float _s1 = (s##S##1); _Float16 _h1 = (_Float16)_s1;                       \
    _Float16 _b1 = (_Float16)(-(z##S##1) * _s1);                               \
    h2 _sv1 = {_h1, _h1}, _bv1 = {_b1, _b1};                                   \
    _o.x = dq2((q##S##2).x, (q##S##2).y, _sv1, _bv1);                          \
    _o.y = dq2((q##S##2).z, (q##S##2).w, _sv1, _bv1);                          \
    _o.z = dq2((q##S##3).x, (q##S##3).y, _sv1, _bv1);                          \
    _o.w = dq2((q##S##3).z, (q##S##3).w, _sv1, _bv1);                          \
    *(int4*)&Bs[buf][(rg + 32) * BK + xo] = _o;                                \
} while (0)

__global__ __launch_bounds__(256, 3) void qlin_mfma5(
    const _Float16* __restrict__ xh, const int* __restrict__ qw,
    const float* __restrict__ sc, const float* __restrict__ zpt,
    const float* __restrict__ bias, float* __restrict__ out)
{
    __shared__ __align__(16) _Float16 As[2][BM * BK];
    __shared__ __align__(16) _Float16 Bs[2][BN * BK];

    const int tid = threadIdx.x;
    int L = blockIdx.x, strip, mblk;
    if (L < 672) { int p = L >> 5, i = L & 31; strip = p * 8 + (i & 7); mblk = i >> 3; }
    else         { int i = L - 672;            strip = 168 + (i & 3);   mblk = i >> 2; }
    const int m0 = mblk * BM;
    const int n0 = strip * BN;

    const int lane = tid & 63;
    const int w    = tid >> 6;
    const int wm   = (w & 1) * 64;
    const int wn   = (w >> 1) * 32;
    const int l16  = lane & 15;
    const int quad = lane >> 4;

    const int c8 = tid & 7;
    const int rg = tid >> 3;
    const int xo = (c8 ^ (rg & 7)) << 3;

    int4 aP0, aP1, aP2, aP3;
    int4 qA0, qA1, qA2, qA3; float sA0, sA1, zA0, zA1;
    int4 qB0, qB1, qB2, qB3; float sB0, sB1, zB0, zB1;

    f32x4 acc[4][2];
#pragma unroll
    for (int mt = 0; mt < 4; ++mt)
#pragma unroll
        for (int nt = 0; nt < 2; ++nt)
            acc[mt][nt] = (f32x4){0.f, 0.f, 0.f, 0.f};

    auto compute = [&](int buf) {
#pragma unroll
        for (int ks = 0; ks < 2; ++ks) {
            half8 a[4], b[2];
            const int ck = ks * 4 + quad;
#pragma unroll
            for (int mt = 0; mt < 4; ++mt) {
                int row = wm + mt * 16 + l16;
                a[mt] = *(const half8*)&As[buf][row * BK + ((ck ^ (row & 7)) << 3)];
            }
#pragma unroll
            for (int nt = 0; nt < 2; ++nt) {
                int row = wn + nt * 16 + l16;
                b[nt] = *(const half8*)&Bs[buf][row * BK + ((ck ^ (row & 7)) << 3)];
            }
#pragma unroll
            for (int mt = 0; mt < 4; ++mt)
#pragma unroll
                for (int nt = 0; nt < 2; ++nt)
                    acc[mt][nt] = __builtin_amdgcn_mfma_f32_16x16x32_f16(
                        a[mt], b[nt], acc[mt][nt], 0, 0, 0);
        }
    };

    PF_B(0, A);
    PF_A(0);
    PF_B(1, B);
    STAGE_A(0);
    STAGE_B(0, A);
    PF_A(1);
    PF_B(2, A);
    __syncthreads();

#pragma unroll 1
    for (int kt = 0; kt < NKT; kt += 2) {
        {
            STAGE_A(1);
            STAGE_B(1, B);
            int ka = kt + 2 < NKT ? kt + 2 : NKT - 1;
            int kb = kt + 3 < NKT ? kt + 3 : NKT - 1;
            PF_A(ka);
            PF_B(kb, B);
        }
        compute(0);
        __syncthreads();
        if (kt + 2 < NKT) {
            STAGE_A(0);
            STAGE_B(0, A);
            int ka = kt + 3 < NKT ? kt + 3 : NKT - 1;
            int kb = kt + 4 < NKT ? kt + 4 : NKT - 1;
            PF_A(ka);
            PF_B(kb, A);
        }
        compute(1);
        __syncthreads();
    }

#pragma unroll
    for (int nt = 0; nt < 2; ++nt) {
        int n = n0 + wn + nt * 16 + l16;
        float bv = bias[n];
#pragma unroll
        for (int mt = 0; mt < 4; ++mt) {
            int mb = m0 + wm + mt * 16 + quad * 4;
#pragma unroll
            for (int r = 0; r < 4; ++r)
                out[(size_t)(mb + r) * OUT_F + n] = acc[mt][nt][r] + bv;
        }
    }
}

// ---------- fallback 2 (no workspace): fp32 x, dist-1 ----------------------
__global__ __launch_bounds__(256, 3) void qlin_mfma4(
    const float* __restrict__ x, const int* __restrict__ qw,
    const float* __restrict__ sc, const float* __restrict__ zpt,
    const float* __restrict__ bias, float* __restrict__ out)
{
    __shared__ __align__(16) _Float16 As[2][BM * BK];
    __shared__ __align__(16) _Float16 Bs[2][BN * BK];

    const int tid = threadIdx.x;
    int L = blockIdx.x, strip, mblk;
    if (L < 672) { int p = L >> 5, i = L & 31; strip = p * 8 + (i & 7); mblk = i >> 3; }
    else         { int i = L - 672;            strip = 168 + (i & 3);   mblk = i >> 2; }
    const int m0 = mblk * BM;
    const int n0 = strip * BN;

    const int lane = tid & 63;
    const int w    = tid >> 6;
    const int wm   = (w & 1) * 64;
    const int wn   = (w >> 1) * 32;
    const int l16  = lane & 15;
    const int quad = lane >> 4;

    const int c8 = tid & 7;
    const int rg = tid >> 3;

    float4 aP[8];
    int4   bP[4];
    float  sP[2], zP[2];

    auto pf = [&](int kt) {
        const int k0 = kt * BK;
        const int g  = kt >> 1;
#pragma unroll
        for (int j = 0; j < 4; ++j) {
            int row = rg + 32 * j;
            const float4* p = (const float4*)(x + (size_t)(m0 + row) * IN_F + k0 + c8 * 8);
            aP[2 * j]     = p[0];
            aP[2 * j + 1] = p[1];
        }
#pragma unroll
        for (int j = 0; j < 2; ++j) {
            int row = n0 + rg + 32 * j;
            const int4* p = (const int4*)(qw + (size_t)row * IN_F + k0 + c8 * 8);
            bP[2 * j]     = p[0];
            bP[2 * j + 1] = p[1];
            sP[j] = sc [(size_t)row * NG + g];
            zP[j] = zpt[(size_t)row * NG + g];
        }
    };

    auto stage = [&](int buf) {
#pragma unroll
        for (int j = 0; j < 4; ++j) {
            int row = rg + 32 * j;
            float4 f0 = aP[2 * j], f1 = aP[2 * j + 1];
            int4 o;
            o.x = __builtin_bit_cast(int, __builtin_amdgcn_cvt_pkrtz(f0.x, f0.y));
            o.y = __builtin_bit_cast(int, __builtin_amdgcn_cvt_pkrtz(f0.z, f0.w));
            o.z = __builtin_bit_cast(int, __builtin_amdgcn_cvt_pkrtz(f1.x, f1.y));
            o.w = __builtin_bit_cast(int, __builtin_amdgcn_cvt_pkrtz(f1.z, f1.w));
            *(int4*)&As[buf][row * BK + ((c8 ^ (row & 7)) << 3)] = o;
        }
#pragma unroll
        for (int j = 0; j < 2; ++j) {
            int row = rg + 32 * j;
            float sf = sP[j];
            _Float16 sh = (_Float16)sf;
            _Float16 bh = (_Float16)(-zP[j] * sf);
            h2 sv = {sh, sh}, bv = {bh, bh};
            int4 q0 = bP[2 * j], q1 = bP[2 * j + 1];
            int4 o;
            o.x = dq2(q0.x, q0.y, sv, bv);
            o.y = dq2(q0.z, q0.w, sv, bv);
            o.z = dq2(q1.x, q1.y, sv, bv);
            o.w = dq2(q1.z, q1.w, sv, bv);
            *(int4*)&Bs[buf][row * BK + ((c8 ^ (row & 7)) << 3)] = o;
        }
    };

    f32x4 acc[4][2];
#pragma unroll
    for (int mt = 0; mt < 4; ++mt)
#pragma unroll
        for (int nt = 0; nt < 2; ++nt)
            acc[mt][nt] = (f32x4){0.f, 0.f, 0.f, 0.f};

    auto compute = [&](int buf) {
#pragma unroll
        for (int ks = 0; ks < 2; ++ks) {
            half8 a[4], b[2];
            const int ck = ks * 4 + quad;
#pragma unroll
            for (int mt = 0; mt < 4; ++mt) {
                int row = wm + mt * 16 + l16;
                a[mt] = *(const half8*)&As[buf][row * BK + ((ck ^ (row & 7)) << 3)];
            }
#pragma unroll
            for (int nt = 0; nt < 2; ++nt) {
                int row = wn + nt * 16 + l16;
                b[nt] = *(const half8*)&Bs[buf][row * BK + ((ck ^ (row & 7)) << 3)];
            }
#pragma unroll
            for (int mt = 0; mt < 4; ++mt)
#pragma unroll
                for (int nt = 0; nt < 2; ++nt)
                    acc[mt][nt] = __builtin_amdgcn_mfma_f32_16x16x32_f16(
                        a[mt], b[nt], acc[mt][nt], 0, 0, 0);
        }
    };

    pf(0);
    stage(0);
    __syncthreads();

#pragma unroll 1
    for (int kt = 0; kt < NKT; ++kt) {
        const int buf = kt & 1;
        if (kt + 1 < NKT) {
            pf(kt + 1);
            compute(buf);
            stage(buf ^ 1);
            __syncthreads();
        } else {
            compute(buf);
        }
    }

#pragma unroll
    for (int nt = 0; nt < 2; ++nt) {
        int n = n0 + wn + nt * 16 + l16;
        float bv = bias[n];
#pragma unroll
        for (int mt = 0; mt < 4; ++mt) {
            int mb = m0 + wm + mt * 16 + quad * 4;
#pragma unroll
            for (int r = 0; r < 4; ++r)
                out[(size_t)(mb + r) * OUT_F + n] = acc[mt][nt][r] + bv;
        }
    }
}

extern "C" void kernel_launch(void* const* d_in, const int* in_sizes, int n_in,
                              void* d_out, int out_size, void* d_ws, size_t ws_size,
                              hipStream_t stream) {
    const float* x    = (const float*)d_in[0];
    const int*   qw   = (const int*)d_in[1];
    const float* scp  = (const float*)d_in[2];
    const float* zpp  = (const float*)d_in[3];
    const float* bias = (const float*)d_in[4];
    float* out = (float*)d_out;
    (void)in_sizes; (void)n_in; (void)out_size;

    const size_t XH_BYTES = (size_t)512 * IN_F * sizeof(_Float16);   // 4 MB
    const size_t PW_BYTES = (size_t)OUT_F * IN_F / 2;                // 22.5 MB

    if (ws_size >= XH_BYTES + PW_BYTES) {
        _Float16* xh  = (_Float16*)d_ws;
        uint32_t* pwT = (uint32_t*)((char*)d_ws + XH_BYTES);
        prep_all<<<dim3(1024 + 2752), dim3(256), 0, stream>>>(x, xh, qw, pwT);
        qlin_mfma12<<<dim3(NBLK), dim3(256), 0, stream>>>(xh, pwT, scp, zpp, bias, out);
    } else if (ws_size >= XH_BYTES) {
        _Float16* xh = (_Float16*)d_ws;
        cvt_x<<<dim3(1024), dim3(256), 0, stream>>>(x, xh);
        qlin_mfma5<<<dim3(NBLK), dim3(256), 0, stream>>>(xh, qw, scp, zpp, bias, out);
    } else {
        qlin_mfma4<<<dim3(NBLK), dim3(256), 0, stream>>>(x, qw, scp, zpp, bias, out);
    }
}